// Round 16
// baseline (447.270 us; speedup 1.0000x reference)
//
#include <hip/hip_runtime.h>

#define KF 128
#define NSUP 256
#define NSPEC 4
#define GRID 512      // 2 blocks per CU (64 KB LDS each)
#define BLOCK 512     // 8 waves; <=512 threads keeps hipcc's register heuristic sane

typedef __bf16 bf16x8 __attribute__((ext_vector_type(8)));
typedef float  f32x4  __attribute__((ext_vector_type(4)));

// ---------------- build per-species Gram matrix, sigma-permuted fragment-major ----------------
// G[s][c][k] = sum_m w[s][m]*sup[s][m][c]*sup[s][m][k]  (fp32 accum -> bf16)
// t = ((s*8+ct)*4+kk)*64+lane holds G[s][sigma(ct,lane&15)][kk*32+(lane>>4)*8+u], u=0..7
// sigma(ct,i) = (ct>>1)*32 + (i>>2)*8 + (ct&1)*4 + (i&3): MFMA D-layout lands z[c] on
// the lane that already holds x[c] -> pairing needs no cross-lane moves.

__global__ void k_buildG(const float* __restrict__ sup, const float* __restrict__ w,
                         __bf16* __restrict__ gfrag) {
    const int t = blockIdx.x * blockDim.x + threadIdx.x;   // 8192 total
    if (t >= NSPEC * 8 * 4 * 64) return;
    const int lane = t & 63;
    const int kk   = (t >> 6) & 3;
    const int ct   = (t >> 8) & 7;
    const int s    = t >> 11;
    const int i    = lane & 15;
    const int c    = (ct >> 1) * 32 + (i >> 2) * 8 + (ct & 1) * 4 + (i & 3);
    const int k0   = kk * 32 + (lane >> 4) * 8;
    const float* S = sup + (size_t)s * NSUP * KF;
    const float* W = w + s * NSUP;
    float a0 = 0.f, a1 = 0.f, a2 = 0.f, a3 = 0.f, a4 = 0.f, a5 = 0.f, a6 = 0.f, a7 = 0.f;
    for (int m = 0; m < NSUP; ++m) {
        const float wc = W[m] * S[m * KF + c];
        const float4 ka = *(const float4*)(S + m * KF + k0);
        const float4 kb = *(const float4*)(S + m * KF + k0 + 4);
        a0 += wc * ka.x; a1 += wc * ka.y; a2 += wc * ka.z; a3 += wc * ka.w;
        a4 += wc * kb.x; a5 += wc * kb.y; a6 += wc * kb.z; a7 += wc * kb.w;
    }
    bf16x8 o;
    o[0] = (__bf16)a0; o[1] = (__bf16)a1; o[2] = (__bf16)a2; o[3] = (__bf16)a3;
    o[4] = (__bf16)a4; o[5] = (__bf16)a5; o[6] = (__bf16)a6; o[7] = (__bf16)a7;
    *(bf16x8*)(gfrag + (size_t)t * 8) = o;
}

// ---------------- helpers ----------------

__device__ __forceinline__ bf16x8 pack8(float4 a, float4 b) {
    bf16x8 o;
    o[0] = (__bf16)a.x; o[1] = (__bf16)a.y; o[2] = (__bf16)a.z; o[3] = (__bf16)a.w;
    o[4] = (__bf16)b.x; o[5] = (__bf16)b.y; o[6] = (__bf16)b.z; o[7] = (__bf16)b.w;
    return o;
}

__device__ __forceinline__ float sq4(float4 a) {
    return a.x * a.x + a.y * a.y + a.z * a.z + a.w * a.w;
}

// Load one 16-atom set: meta + 4 bf16x8 fragments + fp32 norm. Loads are consumed
// pairwise (norm+pack) so the float4 temporaries stay short-lived.
#define LOAD_SET(BASE, OFF, SPC, SID, V, NN, X0, X1, X2, X3)              \
    {                                                                     \
        int _a = (BASE) + (OFF) + r;                                      \
        V = _a < n;                                                       \
        int _ra = V ? _a : 0;                                             \
        SPC = V ? species[_ra] : -1;                                      \
        SID = V ? sids[_ra] : 0;                                          \
        const float* _p = ps + (size_t)_ra * KF + g * 8;                  \
        float4 _q0 = V ? *(const float4*)(_p +   0) : z4;                 \
        float4 _q1 = V ? *(const float4*)(_p +   4) : z4;                 \
        float4 _q2 = V ? *(const float4*)(_p +  32) : z4;                 \
        float4 _q3 = V ? *(const float4*)(_p +  36) : z4;                 \
        float4 _q4 = V ? *(const float4*)(_p +  64) : z4;                 \
        float4 _q5 = V ? *(const float4*)(_p +  68) : z4;                 \
        float4 _q6 = V ? *(const float4*)(_p +  96) : z4;                 \
        float4 _q7 = V ? *(const float4*)(_p + 100) : z4;                 \
        NN = sq4(_q0) + sq4(_q1) + sq4(_q2) + sq4(_q3)                    \
           + sq4(_q4) + sq4(_q5) + sq4(_q6) + sq4(_q7);                   \
        NN += __shfl_xor(NN, 16);                                         \
        NN += __shfl_xor(NN, 32);                                         \
        X0 = pack8(_q0, _q1); X1 = pack8(_q2, _q3);                       \
        X2 = pack8(_q4, _q5); X3 = pack8(_q6, _q7);                       \
    }

// One ct-step for BOTH atom-sets: 4 G-fragment LDS reads feed 8 MFMA.
// Pairing scalars come from fragment XA/XB elements (CT&1)*4 .. +3.
#define GSTEP2(CT, XA, XB)                                                      \
    {                                                                           \
        const __bf16* gq = gp + (CT) * 2048;                                    \
        const bf16x8 g0 = *(const bf16x8*)(gq);                                 \
        const bf16x8 g1 = *(const bf16x8*)(gq + 512);                           \
        const bf16x8 g2 = *(const bf16x8*)(gq + 1024);                          \
        const bf16x8 g3 = *(const bf16x8*)(gq + 1536);                          \
        f32x4 aA = (f32x4){0.f, 0.f, 0.f, 0.f};                                 \
        f32x4 aB = (f32x4){0.f, 0.f, 0.f, 0.f};                                 \
        aA = __builtin_amdgcn_mfma_f32_16x16x32_bf16(g0, cA0, aA, 0, 0, 0);     \
        aB = __builtin_amdgcn_mfma_f32_16x16x32_bf16(g0, cB0, aB, 0, 0, 0);     \
        aA = __builtin_amdgcn_mfma_f32_16x16x32_bf16(g1, cA1, aA, 0, 0, 0);     \
        aB = __builtin_amdgcn_mfma_f32_16x16x32_bf16(g1, cB1, aB, 0, 0, 0);     \
        aA = __builtin_amdgcn_mfma_f32_16x16x32_bf16(g2, cA2, aA, 0, 0, 0);     \
        aB = __builtin_amdgcn_mfma_f32_16x16x32_bf16(g2, cB2, aB, 0, 0, 0);     \
        aA = __builtin_amdgcn_mfma_f32_16x16x32_bf16(g3, cA3, aA, 0, 0, 0);     \
        aB = __builtin_amdgcn_mfma_f32_16x16x32_bf16(g3, cB3, aB, 0, 0, 0);     \
        const int _o = ((CT) & 1) * 4;                                          \
        esA += aA[0] * (float)XA[_o + 0] + aA[1] * (float)XA[_o + 1]            \
             + aA[2] * (float)XA[_o + 2] + aA[3] * (float)XA[_o + 3];           \
        esB += aB[0] * (float)XB[_o + 0] + aB[1] * (float)XB[_o + 1]            \
             + aB[2] * (float)XB[_o + 2] + aB[3] * (float)XB[_o + 3];           \
    }

// ---------------- main kernel: 2 species per block (64 KB LDS -> 2 blocks/CU) ----------------
// Even blocks own species {0,1}, odd blocks {2,3}. Paired blocks (b, b^1) walk the
// SAME tile sequence so the second ps read hits L2/L3.

__global__ __launch_bounds__(BLOCK, 4) void k_main(
    const float* __restrict__ ps,
    const __bf16* __restrict__ gfrag,
    const int* __restrict__ species,
    const int* __restrict__ sids,
    float* __restrict__ out,
    int n)
{
    __shared__ __align__(16) __bf16 Glds[2 * 128 * 128];   // 64 KB (2 species)

    const int spbase = (blockIdx.x & 1) * 2;
    {
        const int4* src = (const int4*)(gfrag + (size_t)spbase * 16384);
        for (int f = threadIdx.x; f < 4096; f += BLOCK)
            ((int4*)Glds)[f] = src[f];
    }
    __syncthreads();

    const int lane = threadIdx.x & 63;
    const int r = lane & 15, g = lane >> 4;
    const int wid = (blockIdx.x >> 1) * (BLOCK / 64) + (threadIdx.x >> 6);
    const int gs = (GRID / 2) * (BLOCK / 64);
    const int ntiles = (n + 31) / 32;

    const float4 z4 = make_float4(0.f, 0.f, 0.f, 0.f);

    for (int t = wid; t < ntiles; t += gs) {
        int spcA, sidA, spcB, sidB;
        bool vA, vB;
        float nnA, nnB;
        bf16x8 cA0, cA1, cA2, cA3, cB0, cB1, cB2, cB3;

        LOAD_SET(t * 32, 0,  spcA, sidA, vA, nnA, cA0, cA1, cA2, cA3)
        LOAD_SET(t * 32, 16, spcB, sidB, vB, nnB, cB0, cB1, cB2, cB3)

        // ---- compute: 2 species x 8 ct-steps, G reads shared by both sets ----
        float eA = 0.f, eB = 0.f;
        #pragma unroll 1
        for (int s = 0; s < 2; ++s) {
            const __bf16* gp = Glds + s * 16384 + lane * 8;
            float esA = 0.f, esB = 0.f;
            GSTEP2(0, cA0, cB0)
            GSTEP2(1, cA0, cB0)
            __builtin_amdgcn_sched_barrier(0);
            GSTEP2(2, cA1, cB1)
            GSTEP2(3, cA1, cB1)
            __builtin_amdgcn_sched_barrier(0);
            GSTEP2(4, cA2, cB2)
            GSTEP2(5, cA2, cB2)
            __builtin_amdgcn_sched_barrier(0);
            GSTEP2(6, cA3, cB3)
            GSTEP2(7, cA3, cB3)
            eA += (spcA == spbase + s) ? esA : 0.f;
            eB += (spcB == spbase + s) ? esB : 0.f;
        }

        float uA = (nnA > 0.f) ? eA / nnA : 0.f;
        float uB = (nnB > 0.f) ? eB / nnB : 0.f;

        // ---- emit (u is zero for atoms of the other species-pair; adding 0 is safe) ----
        const int s0 = __shfl(sidA, 0);
        const bool uni = __all(sidA == s0) && __all(sidB == s0);
        if (uni) {
            float tot = uA + uB;
            tot += __shfl_xor(tot, 1);  tot += __shfl_xor(tot, 2);
            tot += __shfl_xor(tot, 4);  tot += __shfl_xor(tot, 8);
            tot += __shfl_xor(tot, 16); tot += __shfl_xor(tot, 32);
            if (lane == 0 && tot != 0.f) atomicAdd(&out[s0], tot);
        } else {
            uA += __shfl_xor(uA, 16); uA += __shfl_xor(uA, 32);
            uB += __shfl_xor(uB, 16); uB += __shfl_xor(uB, 32);
            if (g == 0) {
                if (vA && uA != 0.f) atomicAdd(&out[sidA], uA);
                if (vB && uB != 0.f) atomicAdd(&out[sidB], uB);
            }
        }
    }
}

// ---------------- slow-but-correct fallback (ws too small) ----------------

__global__ void k_fallback(const float* __restrict__ ps, const float* __restrict__ support,
                           const float* __restrict__ weights, const int* __restrict__ species,
                           const int* __restrict__ struct_ids, float* __restrict__ out, int n)
{
    int gw = (blockIdx.x * blockDim.x + threadIdx.x) >> 6;
    int lane = threadIdx.x & 63;
    int nw = (gridDim.x * blockDim.x) >> 6;
    for (int atom = gw; atom < n; atom += nw) {
        const float* row = ps + (size_t)atom * KF;
        float x0 = row[lane], x1 = row[lane + 64];
        float nsum = x0 * x0 + x1 * x1;
        for (int o = 32; o; o >>= 1) nsum += __shfl_xor(nsum, o);
        float iv2 = 1.0f / nsum;
        int s = species[atom];
        const float* sup = support + (size_t)s * NSUP * KF;
        const float* w = weights + (size_t)s * NSUP;
        float e = 0.f;
        for (int mm = 0; mm < 4; ++mm) {
            int m = lane + mm * 64;
            const float* srow = sup + (size_t)m * KF;
            float d = 0.f;
            for (int k = 0; k < KF; ++k) d += row[k] * srow[k];
            e += d * d * w[m];
        }
        for (int o = 32; o; o >>= 1) e += __shfl_xor(e, o);
        if (lane == 0) atomicAdd(&out[struct_ids[atom]], e * iv2);
    }
}

// ---------------- launch ----------------

extern "C" void kernel_launch(void* const* d_in, const int* in_sizes, int n_in,
                              void* d_out, int out_size, void* d_ws, size_t ws_size,
                              hipStream_t stream)
{
    const float* ps       = (const float*)d_in[0];
    const float* support  = (const float*)d_in[1];
    const float* weights  = (const float*)d_in[2];
    const int*   species  = (const int*)d_in[3];
    const int*   sids     = (const int*)d_in[4];
    float* out = (float*)d_out;
    const int n = in_sizes[0] / KF;

    hipMemsetAsync(d_out, 0, (size_t)out_size * sizeof(float), stream);

    const size_t gbytes = (size_t)NSPEC * 8 * 4 * 64 * 8 * sizeof(__bf16);   // 128 KB
    if (ws_size < gbytes) {
        k_fallback<<<2048, 256, 0, stream>>>(ps, support, weights, species, sids, out, n);
        return;
    }

    __bf16* gfrag = (__bf16*)d_ws;
    k_buildG<<<(NSPEC * 8 * 4 * 64 + 255) / 256, 256, 0, stream>>>(support, weights, gfrag);
    k_main<<<GRID, BLOCK, 0, stream>>>(ps, gfrag, species, sids, out, n);
}

// Round 17
// 301.854 us; speedup vs baseline: 1.4817x; 1.4817x over previous
//
#include <hip/hip_runtime.h>

#define KF 128
#define NSUP 256
#define NSPEC 4
#define GRID 512      // 2 blocks per CU (64 KB LDS each)
#define BLOCK 512     // 8 waves; <=512 threads + min-waves=1 keeps hipcc's
                      // register allocator sane (r15: VGPR 104, zero spill;
                      // min-waves>=4 or >=768-thread blocks clamp to 64 and spill GBs)

typedef __bf16 bf16x8 __attribute__((ext_vector_type(8)));
typedef float  f32x4  __attribute__((ext_vector_type(4)));

// ---------------- build per-species Gram matrix, sigma-permuted fragment-major ----------------
// G[s][c][k] = sum_m w[s][m]*sup[s][m][c]*sup[s][m][k]  (fp32 accum -> bf16)
// t = ((s*8+ct)*4+kk)*64+lane holds G[s][sigma(ct,lane&15)][kk*32+(lane>>4)*8+u], u=0..7
// sigma(ct,i) = (ct>>1)*32 + (i>>2)*8 + (ct&1)*4 + (i&3): MFMA D-layout lands z[c] on
// the lane that already holds x[c] -> pairing needs no cross-lane moves.

__global__ void k_buildG(const float* __restrict__ sup, const float* __restrict__ w,
                         __bf16* __restrict__ gfrag) {
    const int t = blockIdx.x * blockDim.x + threadIdx.x;   // 8192 total
    if (t >= NSPEC * 8 * 4 * 64) return;
    const int lane = t & 63;
    const int kk   = (t >> 6) & 3;
    const int ct   = (t >> 8) & 7;
    const int s    = t >> 11;
    const int i    = lane & 15;
    const int c    = (ct >> 1) * 32 + (i >> 2) * 8 + (ct & 1) * 4 + (i & 3);
    const int k0   = kk * 32 + (lane >> 4) * 8;
    const float* S = sup + (size_t)s * NSUP * KF;
    const float* W = w + s * NSUP;
    float a0 = 0.f, a1 = 0.f, a2 = 0.f, a3 = 0.f, a4 = 0.f, a5 = 0.f, a6 = 0.f, a7 = 0.f;
    for (int m = 0; m < NSUP; ++m) {
        const float wc = W[m] * S[m * KF + c];
        const float4 ka = *(const float4*)(S + m * KF + k0);
        const float4 kb = *(const float4*)(S + m * KF + k0 + 4);
        a0 += wc * ka.x; a1 += wc * ka.y; a2 += wc * ka.z; a3 += wc * ka.w;
        a4 += wc * kb.x; a5 += wc * kb.y; a6 += wc * kb.z; a7 += wc * kb.w;
    }
    bf16x8 o;
    o[0] = (__bf16)a0; o[1] = (__bf16)a1; o[2] = (__bf16)a2; o[3] = (__bf16)a3;
    o[4] = (__bf16)a4; o[5] = (__bf16)a5; o[6] = (__bf16)a6; o[7] = (__bf16)a7;
    *(bf16x8*)(gfrag + (size_t)t * 8) = o;
}

// ---------------- helpers ----------------

__device__ __forceinline__ bf16x8 pack8(float4 a, float4 b) {
    bf16x8 o;
    o[0] = (__bf16)a.x; o[1] = (__bf16)a.y; o[2] = (__bf16)a.z; o[3] = (__bf16)a.w;
    o[4] = (__bf16)b.x; o[5] = (__bf16)b.y; o[6] = (__bf16)b.z; o[7] = (__bf16)b.w;
    return o;
}

__device__ __forceinline__ float sq4(float4 a) {
    return a.x * a.x + a.y * a.y + a.z * a.z + a.w * a.w;
}

// Load one 16-atom set: meta + 4 bf16x8 fragments + fp32 norm. Loads are consumed
// pairwise (norm+pack) so the float4 temporaries stay short-lived.
#define LOAD_SET(BASE, OFF, SPC, SID, V, NN, X0, X1, X2, X3)              \
    {                                                                     \
        int _a = (BASE) + (OFF) + r;                                      \
        V = _a < n;                                                       \
        int _ra = V ? _a : 0;                                             \
        SPC = V ? species[_ra] : -1;                                      \
        SID = V ? sids[_ra] : 0;                                          \
        const float* _p = ps + (size_t)_ra * KF + g * 8;                  \
        float4 _q0 = V ? *(const float4*)(_p +   0) : z4;                 \
        float4 _q1 = V ? *(const float4*)(_p +   4) : z4;                 \
        float4 _q2 = V ? *(const float4*)(_p +  32) : z4;                 \
        float4 _q3 = V ? *(const float4*)(_p +  36) : z4;                 \
        float4 _q4 = V ? *(const float4*)(_p +  64) : z4;                 \
        float4 _q5 = V ? *(const float4*)(_p +  68) : z4;                 \
        float4 _q6 = V ? *(const float4*)(_p +  96) : z4;                 \
        float4 _q7 = V ? *(const float4*)(_p + 100) : z4;                 \
        NN = sq4(_q0) + sq4(_q1) + sq4(_q2) + sq4(_q3)                    \
           + sq4(_q4) + sq4(_q5) + sq4(_q6) + sq4(_q7);                   \
        NN += __shfl_xor(NN, 16);                                         \
        NN += __shfl_xor(NN, 32);                                         \
        X0 = pack8(_q0, _q1); X1 = pack8(_q2, _q3);                       \
        X2 = pack8(_q4, _q5); X3 = pack8(_q6, _q7);                       \
    }

// One ct-step for BOTH atom-sets: 4 G-fragment LDS reads feed 8 MFMA.
// Pairing scalars come from fragment XA/XB elements (CT&1)*4 .. +3.
#define GSTEP2(CT, XA, XB)                                                      \
    {                                                                           \
        const __bf16* gq = gp + (CT) * 2048;                                    \
        const bf16x8 g0 = *(const bf16x8*)(gq);                                 \
        const bf16x8 g1 = *(const bf16x8*)(gq + 512);                           \
        const bf16x8 g2 = *(const bf16x8*)(gq + 1024);                          \
        const bf16x8 g3 = *(const bf16x8*)(gq + 1536);                          \
        f32x4 aA = (f32x4){0.f, 0.f, 0.f, 0.f};                                 \
        f32x4 aB = (f32x4){0.f, 0.f, 0.f, 0.f};                                 \
        aA = __builtin_amdgcn_mfma_f32_16x16x32_bf16(g0, cA0, aA, 0, 0, 0);     \
        aB = __builtin_amdgcn_mfma_f32_16x16x32_bf16(g0, cB0, aB, 0, 0, 0);     \
        aA = __builtin_amdgcn_mfma_f32_16x16x32_bf16(g1, cA1, aA, 0, 0, 0);     \
        aB = __builtin_amdgcn_mfma_f32_16x16x32_bf16(g1, cB1, aB, 0, 0, 0);     \
        aA = __builtin_amdgcn_mfma_f32_16x16x32_bf16(g2, cA2, aA, 0, 0, 0);     \
        aB = __builtin_amdgcn_mfma_f32_16x16x32_bf16(g2, cB2, aB, 0, 0, 0);     \
        aA = __builtin_amdgcn_mfma_f32_16x16x32_bf16(g3, cA3, aA, 0, 0, 0);     \
        aB = __builtin_amdgcn_mfma_f32_16x16x32_bf16(g3, cB3, aB, 0, 0, 0);     \
        const int _o = ((CT) & 1) * 4;                                          \
        esA += aA[0] * (float)XA[_o + 0] + aA[1] * (float)XA[_o + 1]            \
             + aA[2] * (float)XA[_o + 2] + aA[3] * (float)XA[_o + 3];           \
        esB += aB[0] * (float)XB[_o + 0] + aB[1] * (float)XB[_o + 1]            \
             + aB[2] * (float)XB[_o + 2] + aB[3] * (float)XB[_o + 3];           \
    }

// ---------------- main kernel: 2 species per block (64 KB LDS -> 2 blocks/CU) ----------------
// Even blocks own species {0,1}, odd blocks {2,3}. Paired blocks (b, b^1) walk the
// SAME tile sequence so the second ps read hits L2/L3.

__global__ __launch_bounds__(BLOCK, 1) void k_main(
    const float* __restrict__ ps,
    const __bf16* __restrict__ gfrag,
    const int* __restrict__ species,
    const int* __restrict__ sids,
    float* __restrict__ out,
    int n)
{
    __shared__ __align__(16) __bf16 Glds[2 * 128 * 128];   // 64 KB (2 species)

    const int spbase = (blockIdx.x & 1) * 2;
    {
        const int4* src = (const int4*)(gfrag + (size_t)spbase * 16384);
        for (int f = threadIdx.x; f < 4096; f += BLOCK)
            ((int4*)Glds)[f] = src[f];
    }
    __syncthreads();

    const int lane = threadIdx.x & 63;
    const int r = lane & 15, g = lane >> 4;
    const int wid = (blockIdx.x >> 1) * (BLOCK / 64) + (threadIdx.x >> 6);
    const int gs = (GRID / 2) * (BLOCK / 64);
    const int ntiles = (n + 31) / 32;

    const float4 z4 = make_float4(0.f, 0.f, 0.f, 0.f);

    for (int t = wid; t < ntiles; t += gs) {
        int spcA, sidA, spcB, sidB;
        bool vA, vB;
        float nnA, nnB;
        bf16x8 cA0, cA1, cA2, cA3, cB0, cB1, cB2, cB3;

        LOAD_SET(t * 32, 0,  spcA, sidA, vA, nnA, cA0, cA1, cA2, cA3)
        LOAD_SET(t * 32, 16, spcB, sidB, vB, nnB, cB0, cB1, cB2, cB3)

        // ---- compute: 2 species x 8 ct-steps, G reads shared by both sets ----
        float eA = 0.f, eB = 0.f;
        #pragma unroll 1
        for (int s = 0; s < 2; ++s) {
            const __bf16* gp = Glds + s * 16384 + lane * 8;
            float esA = 0.f, esB = 0.f;
            GSTEP2(0, cA0, cB0)
            GSTEP2(1, cA0, cB0)
            __builtin_amdgcn_sched_barrier(0);
            GSTEP2(2, cA1, cB1)
            GSTEP2(3, cA1, cB1)
            __builtin_amdgcn_sched_barrier(0);
            GSTEP2(4, cA2, cB2)
            GSTEP2(5, cA2, cB2)
            __builtin_amdgcn_sched_barrier(0);
            GSTEP2(6, cA3, cB3)
            GSTEP2(7, cA3, cB3)
            eA += (spcA == spbase + s) ? esA : 0.f;
            eB += (spcB == spbase + s) ? esB : 0.f;
        }

        float uA = (nnA > 0.f) ? eA / nnA : 0.f;
        float uB = (nnB > 0.f) ? eB / nnB : 0.f;

        // ---- emit (u is zero for atoms of the other species-pair; adding 0 is safe) ----
        const int s0 = __shfl(sidA, 0);
        const bool uni = __all(sidA == s0) && __all(sidB == s0);
        if (uni) {
            float tot = uA + uB;
            tot += __shfl_xor(tot, 1);  tot += __shfl_xor(tot, 2);
            tot += __shfl_xor(tot, 4);  tot += __shfl_xor(tot, 8);
            tot += __shfl_xor(tot, 16); tot += __shfl_xor(tot, 32);
            if (lane == 0 && tot != 0.f) atomicAdd(&out[s0], tot);
        } else {
            uA += __shfl_xor(uA, 16); uA += __shfl_xor(uA, 32);
            uB += __shfl_xor(uB, 16); uB += __shfl_xor(uB, 32);
            if (g == 0) {
                if (vA && uA != 0.f) atomicAdd(&out[sidA], uA);
                if (vB && uB != 0.f) atomicAdd(&out[sidB], uB);
            }
        }
    }
}

// ---------------- slow-but-correct fallback (ws too small) ----------------

__global__ void k_fallback(const float* __restrict__ ps, const float* __restrict__ support,
                           const float* __restrict__ weights, const int* __restrict__ species,
                           const int* __restrict__ struct_ids, float* __restrict__ out, int n)
{
    int gw = (blockIdx.x * blockDim.x + threadIdx.x) >> 6;
    int lane = threadIdx.x & 63;
    int nw = (gridDim.x * blockDim.x) >> 6;
    for (int atom = gw; atom < n; atom += nw) {
        const float* row = ps + (size_t)atom * KF;
        float x0 = row[lane], x1 = row[lane + 64];
        float nsum = x0 * x0 + x1 * x1;
        for (int o = 32; o; o >>= 1) nsum += __shfl_xor(nsum, o);
        float iv2 = 1.0f / nsum;
        int s = species[atom];
        const float* sup = support + (size_t)s * NSUP * KF;
        const float* w = weights + (size_t)s * NSUP;
        float e = 0.f;
        for (int mm = 0; mm < 4; ++mm) {
            int m = lane + mm * 64;
            const float* srow = sup + (size_t)m * KF;
            float d = 0.f;
            for (int k = 0; k < KF; ++k) d += row[k] * srow[k];
            e += d * d * w[m];
        }
        for (int o = 32; o; o >>= 1) e += __shfl_xor(e, o);
        if (lane == 0) atomicAdd(&out[struct_ids[atom]], e * iv2);
    }
}

// ---------------- launch ----------------

extern "C" void kernel_launch(void* const* d_in, const int* in_sizes, int n_in,
                              void* d_out, int out_size, void* d_ws, size_t ws_size,
                              hipStream_t stream)
{
    const float* ps       = (const float*)d_in[0];
    const float* support  = (const float*)d_in[1];
    const float* weights  = (const float*)d_in[2];
    const int*   species  = (const int*)d_in[3];
    const int*   sids     = (const int*)d_in[4];
    float* out = (float*)d_out;
    const int n = in_sizes[0] / KF;

    hipMemsetAsync(d_out, 0, (size_t)out_size * sizeof(float), stream);

    const size_t gbytes = (size_t)NSPEC * 8 * 4 * 64 * 8 * sizeof(__bf16);   // 128 KB
    if (ws_size < gbytes) {
        k_fallback<<<2048, 256, 0, stream>>>(ps, support, weights, species, sids, out, n);
        return;
    }

    __bf16* gfrag = (__bf16*)d_ws;
    k_buildG<<<(NSPEC * 8 * 4 * 64 + 255) / 256, 256, 0, stream>>>(support, weights, gfrag);
    k_main<<<GRID, BLOCK, 0, stream>>>(ps, gfrag, species, sids, out, n);
}

// Round 18
// 294.958 us; speedup vs baseline: 1.5164x; 1.0234x over previous
//
#include <hip/hip_runtime.h>

#define KF 128
#define NSUP 256
#define NSPEC 4
#define GRID 1024     // 4 blocks/CU; blockIdx&3 = species
#define BLOCK 256     // 4 waves; small blocks keep hipcc's register allocator sane

typedef __bf16 bf16x8 __attribute__((ext_vector_type(8)));
typedef float  f32x4  __attribute__((ext_vector_type(4)));

// ---------------- species bucketing ----------------

__global__ void k_count(const int* __restrict__ sp, int n, int* __restrict__ counts) {
    __shared__ int h[NSPEC];
    if (threadIdx.x < NSPEC) h[threadIdx.x] = 0;
    __syncthreads();
    for (int i = blockIdx.x * blockDim.x + threadIdx.x; i < n; i += gridDim.x * blockDim.x)
        atomicAdd(&h[sp[i]], 1);
    __syncthreads();
    if (threadIdx.x < NSPEC) atomicAdd(&counts[threadIdx.x], h[threadIdx.x]);
}

__global__ void k_scatter(const int* __restrict__ sp, int n,
                          const int* __restrict__ counts, int* __restrict__ cursors,
                          int* __restrict__ order) {
    __shared__ int lh[NSPEC];
    __shared__ int basep[NSPEC];
    if (threadIdx.x < NSPEC) lh[threadIdx.x] = 0;
    __syncthreads();
    int i = blockIdx.x * blockDim.x + threadIdx.x;
    int s = (i < n) ? sp[i] : -1;
    int local = 0;
    if (s >= 0) local = atomicAdd(&lh[s], 1);
    __syncthreads();
    if (threadIdx.x < NSPEC) {
        int q = threadIdx.x;
        int off = 0;
        for (int u = 0; u < q; ++u) off += counts[u];
        basep[q] = off + atomicAdd(&cursors[q], lh[q]);
    }
    __syncthreads();
    if (s >= 0) order[basep[s] + local] = i;
}

// ---------------- build per-species Gram matrix, sigma-permuted fragment-major ----------------
// G[s][c][k] = sum_m w[s][m]*sup[s][m][c]*sup[s][m][k]  (fp32 accum -> bf16)
// t = ((s*8+ct)*4+kk)*64+lane holds G[s][sigma(ct,lane&15)][kk*32+(lane>>4)*8+u], u=0..7
// sigma(ct,i) = (ct>>1)*32 + (i>>2)*8 + (ct&1)*4 + (i&3): MFMA D-layout lands z[c] on
// the lane that already holds x[c] -> pairing needs no cross-lane moves.

__global__ void k_buildG(const float* __restrict__ sup, const float* __restrict__ w,
                         __bf16* __restrict__ gfrag) {
    const int t = blockIdx.x * blockDim.x + threadIdx.x;   // 8192 total
    if (t >= NSPEC * 8 * 4 * 64) return;
    const int lane = t & 63;
    const int kk   = (t >> 6) & 3;
    const int ct   = (t >> 8) & 7;
    const int s    = t >> 11;
    const int i    = lane & 15;
    const int c    = (ct >> 1) * 32 + (i >> 2) * 8 + (ct & 1) * 4 + (i & 3);
    const int k0   = kk * 32 + (lane >> 4) * 8;
    const float* S = sup + (size_t)s * NSUP * KF;
    const float* W = w + s * NSUP;
    float a0 = 0.f, a1 = 0.f, a2 = 0.f, a3 = 0.f, a4 = 0.f, a5 = 0.f, a6 = 0.f, a7 = 0.f;
    for (int m = 0; m < NSUP; ++m) {
        const float wc = W[m] * S[m * KF + c];
        const float4 ka = *(const float4*)(S + m * KF + k0);
        const float4 kb = *(const float4*)(S + m * KF + k0 + 4);
        a0 += wc * ka.x; a1 += wc * ka.y; a2 += wc * ka.z; a3 += wc * ka.w;
        a4 += wc * kb.x; a5 += wc * kb.y; a6 += wc * kb.z; a7 += wc * kb.w;
    }
    bf16x8 o;
    o[0] = (__bf16)a0; o[1] = (__bf16)a1; o[2] = (__bf16)a2; o[3] = (__bf16)a3;
    o[4] = (__bf16)a4; o[5] = (__bf16)a5; o[6] = (__bf16)a6; o[7] = (__bf16)a7;
    *(bf16x8*)(gfrag + (size_t)t * 8) = o;
}

// ---------------- helpers ----------------

__device__ __forceinline__ bf16x8 pack8(float4 a, float4 b) {
    bf16x8 o;
    o[0] = (__bf16)a.x; o[1] = (__bf16)a.y; o[2] = (__bf16)a.z; o[3] = (__bf16)a.w;
    o[4] = (__bf16)b.x; o[5] = (__bf16)b.y; o[6] = (__bf16)b.z; o[7] = (__bf16)b.w;
    return o;
}

__device__ __forceinline__ float sq4(float4 a) {
    return a.x * a.x + a.y * a.y + a.z * a.z + a.w * a.w;
}

// Load one 16-atom set of this block's species bucket.
// LOC = position within bucket; atom = order[off + LOC + r].
#define LOAD_SET(LOC, SID, V, NN, X0, X1, X2, X3)                         \
    {                                                                     \
        int _l = (LOC) + r;                                               \
        V = _l < cnt;                                                     \
        int _ra = V ? order[off + _l] : 0;                                \
        SID = V ? sids[_ra] : 0;                                          \
        const float* _p = ps + (size_t)_ra * KF + g * 8;                  \
        float4 _q0 = V ? *(const float4*)(_p +   0) : z4;                 \
        float4 _q1 = V ? *(const float4*)(_p +   4) : z4;                 \
        float4 _q2 = V ? *(const float4*)(_p +  32) : z4;                 \
        float4 _q3 = V ? *(const float4*)(_p +  36) : z4;                 \
        float4 _q4 = V ? *(const float4*)(_p +  64) : z4;                 \
        float4 _q5 = V ? *(const float4*)(_p +  68) : z4;                 \
        float4 _q6 = V ? *(const float4*)(_p +  96) : z4;                 \
        float4 _q7 = V ? *(const float4*)(_p + 100) : z4;                 \
        NN = sq4(_q0) + sq4(_q1) + sq4(_q2) + sq4(_q3)                    \
           + sq4(_q4) + sq4(_q5) + sq4(_q6) + sq4(_q7);                   \
        NN += __shfl_xor(NN, 16);                                         \
        NN += __shfl_xor(NN, 32);                                         \
        X0 = pack8(_q0, _q1); X1 = pack8(_q2, _q3);                       \
        X2 = pack8(_q4, _q5); X3 = pack8(_q6, _q7);                       \
    }

// One ct-step for BOTH atom-sets: 4 G-fragment LDS reads feed 8 MFMA.
// Pairing scalars come from fragment XA/XB elements (CT&1)*4 .. +3.
#define GSTEP2(CT, XA, XB)                                                      \
    {                                                                           \
        const __bf16* gq = gp + (CT) * 2048;                                    \
        const bf16x8 g0 = *(const bf16x8*)(gq);                                 \
        const bf16x8 g1 = *(const bf16x8*)(gq + 512);                           \
        const bf16x8 g2 = *(const bf16x8*)(gq + 1024);                          \
        const bf16x8 g3 = *(const bf16x8*)(gq + 1536);                          \
        f32x4 aA = (f32x4){0.f, 0.f, 0.f, 0.f};                                 \
        f32x4 aB = (f32x4){0.f, 0.f, 0.f, 0.f};                                 \
        aA = __builtin_amdgcn_mfma_f32_16x16x32_bf16(g0, cA0, aA, 0, 0, 0);     \
        aB = __builtin_amdgcn_mfma_f32_16x16x32_bf16(g0, cB0, aB, 0, 0, 0);     \
        aA = __builtin_amdgcn_mfma_f32_16x16x32_bf16(g1, cA1, aA, 0, 0, 0);     \
        aB = __builtin_amdgcn_mfma_f32_16x16x32_bf16(g1, cB1, aB, 0, 0, 0);     \
        aA = __builtin_amdgcn_mfma_f32_16x16x32_bf16(g2, cA2, aA, 0, 0, 0);     \
        aB = __builtin_amdgcn_mfma_f32_16x16x32_bf16(g2, cB2, aB, 0, 0, 0);     \
        aA = __builtin_amdgcn_mfma_f32_16x16x32_bf16(g3, cA3, aA, 0, 0, 0);     \
        aB = __builtin_amdgcn_mfma_f32_16x16x32_bf16(g3, cB3, aB, 0, 0, 0);     \
        const int _o = ((CT) & 1) * 4;                                          \
        esA += aA[0] * (float)XA[_o + 0] + aA[1] * (float)XA[_o + 1]            \
             + aA[2] * (float)XA[_o + 2] + aA[3] * (float)XA[_o + 3];           \
        esB += aB[0] * (float)XB[_o + 0] + aB[1] * (float)XB[_o + 1]            \
             + aB[2] * (float)XB[_o + 2] + aB[3] * (float)XB[_o + 3];           \
    }

// ---------------- main kernel: species-pure blocks, 32 KB LDS G ----------------
// Block's species = blockIdx & 3; stages only that species's G (32 KB) -> 4 blocks/CU.
// Atoms come from the species bucket (order[]), gathered once, mostly-ascending runs.

__global__ __launch_bounds__(BLOCK, 1) void k_main(
    const float* __restrict__ ps,
    const __bf16* __restrict__ gfrag,
    const int* __restrict__ counts,
    const int* __restrict__ order,
    const int* __restrict__ sids,
    float* __restrict__ out,
    int n)
{
    __shared__ __align__(16) __bf16 Glds[128 * 128];   // 32 KB (one species)

    const int spec = blockIdx.x & 3;
    {
        const int4* src = (const int4*)(gfrag + (size_t)spec * 16384);
        for (int f = threadIdx.x; f < 2048; f += BLOCK)
            ((int4*)Glds)[f] = src[f];
    }
    __syncthreads();

    int off = 0;
    #pragma unroll
    for (int q = 0; q < NSPEC; ++q) { if (q < spec) off += counts[q]; }
    const int cnt = counts[spec];

    const int lane = threadIdx.x & 63;
    const int r = lane & 15, g = lane >> 4;
    const int wsp = (blockIdx.x >> 2) * (BLOCK / 64) + (threadIdx.x >> 6);  // wave id within species
    const int gs = (GRID / 4) * (BLOCK / 64);
    const int ntiles = (cnt + 31) / 32;

    const float4 z4 = make_float4(0.f, 0.f, 0.f, 0.f);

    for (int t = wsp; t < ntiles; t += gs) {
        int sidA, sidB;
        bool vA, vB;
        float nnA, nnB;
        bf16x8 cA0, cA1, cA2, cA3, cB0, cB1, cB2, cB3;

        LOAD_SET(t * 32,      sidA, vA, nnA, cA0, cA1, cA2, cA3)
        LOAD_SET(t * 32 + 16, sidB, vB, nnB, cB0, cB1, cB2, cB3)

        // ---- compute: 8 ct-steps, single species, G reads shared by both sets ----
        const __bf16* gp = Glds + lane * 8;
        float esA = 0.f, esB = 0.f;
        GSTEP2(0, cA0, cB0)
        GSTEP2(1, cA0, cB0)
        __builtin_amdgcn_sched_barrier(0);
        GSTEP2(2, cA1, cB1)
        GSTEP2(3, cA1, cB1)
        __builtin_amdgcn_sched_barrier(0);
        GSTEP2(4, cA2, cB2)
        GSTEP2(5, cA2, cB2)
        __builtin_amdgcn_sched_barrier(0);
        GSTEP2(6, cA3, cB3)
        GSTEP2(7, cA3, cB3)

        float uA = (vA && nnA > 0.f) ? esA / nnA : 0.f;
        float uB = (vB && nnB > 0.f) ? esB / nnB : 0.f;

        // ---- emit ----
        const int s0 = __shfl(sidA, 0);
        const bool uni = __all(sidA == s0) && __all(sidB == s0);
        if (uni) {
            float tot = uA + uB;
            tot += __shfl_xor(tot, 1);  tot += __shfl_xor(tot, 2);
            tot += __shfl_xor(tot, 4);  tot += __shfl_xor(tot, 8);
            tot += __shfl_xor(tot, 16); tot += __shfl_xor(tot, 32);
            if (lane == 0 && tot != 0.f) atomicAdd(&out[s0], tot);
        } else {
            uA += __shfl_xor(uA, 16); uA += __shfl_xor(uA, 32);
            uB += __shfl_xor(uB, 16); uB += __shfl_xor(uB, 32);
            if (g == 0) {
                if (vA) atomicAdd(&out[sidA], uA);
                if (vB) atomicAdd(&out[sidB], uB);
            }
        }
    }
}

// ---------------- slow-but-correct fallback (ws too small) ----------------

__global__ void k_fallback(const float* __restrict__ ps, const float* __restrict__ support,
                           const float* __restrict__ weights, const int* __restrict__ species,
                           const int* __restrict__ struct_ids, float* __restrict__ out, int n)
{
    int gw = (blockIdx.x * blockDim.x + threadIdx.x) >> 6;
    int lane = threadIdx.x & 63;
    int nw = (gridDim.x * blockDim.x) >> 6;
    for (int atom = gw; atom < n; atom += nw) {
        const float* row = ps + (size_t)atom * KF;
        float x0 = row[lane], x1 = row[lane + 64];
        float nsum = x0 * x0 + x1 * x1;
        for (int o = 32; o; o >>= 1) nsum += __shfl_xor(nsum, o);
        float iv2 = 1.0f / nsum;
        int s = species[atom];
        const float* sup = support + (size_t)s * NSUP * KF;
        const float* w = weights + (size_t)s * NSUP;
        float e = 0.f;
        for (int mm = 0; mm < 4; ++mm) {
            int m = lane + mm * 64;
            const float* srow = sup + (size_t)m * KF;
            float d = 0.f;
            for (int k = 0; k < KF; ++k) d += row[k] * srow[k];
            e += d * d * w[m];
        }
        for (int o = 32; o; o >>= 1) e += __shfl_xor(e, o);
        if (lane == 0) atomicAdd(&out[struct_ids[atom]], e * iv2);
    }
}

// ---------------- launch ----------------

extern "C" void kernel_launch(void* const* d_in, const int* in_sizes, int n_in,
                              void* d_out, int out_size, void* d_ws, size_t ws_size,
                              hipStream_t stream)
{
    const float* ps       = (const float*)d_in[0];
    const float* support  = (const float*)d_in[1];
    const float* weights  = (const float*)d_in[2];
    const int*   species  = (const int*)d_in[3];
    const int*   sids     = (const int*)d_in[4];
    float* out = (float*)d_out;
    const int n = in_sizes[0] / KF;

    hipMemsetAsync(d_out, 0, (size_t)out_size * sizeof(float), stream);

    const size_t gbytes = (size_t)NSPEC * 8 * 4 * 64 * 8 * sizeof(__bf16);   // 128 KB
    size_t order_end = 64 + (size_t)n * sizeof(int);
    size_t gfrag_off = (order_end + 15) & ~(size_t)15;
    const size_t need = gfrag_off + gbytes;
    if (ws_size < need) {
        k_fallback<<<2048, 256, 0, stream>>>(ps, support, weights, species, sids, out, n);
        return;
    }

    int* ws      = (int*)d_ws;
    int* counts  = ws;        // [0..3]
    int* cursors = ws + 8;    // [8..11]
    int* order   = ws + 16;
    __bf16* gfrag = (__bf16*)((char*)d_ws + gfrag_off);

    hipMemsetAsync(ws, 0, 64, stream);
    k_count<<<512, 256, 0, stream>>>(species, n, counts);
    k_scatter<<<(n + 255) / 256, 256, 0, stream>>>(species, n, counts, cursors, order);
    k_buildG<<<(NSPEC * 8 * 4 * 64 + 255) / 256, 256, 0, stream>>>(support, weights, gfrag);

    k_main<<<GRID, BLOCK, 0, stream>>>(ps, gfrag, counts, order, sids, out, n);
}

// Round 19
// 235.647 us; speedup vs baseline: 1.8981x; 1.2517x over previous
//
#include <hip/hip_runtime.h>

#define KF 128
#define NSUP 256
#define NSPEC 4
#define GRID 1024     // 4 blocks/CU (32 KB LDS each); blockIdx&3 = species
#define BLOCK 256     // 4 waves; small blocks + min-waves=1 keep hipcc regalloc sane

typedef __bf16 bf16x8 __attribute__((ext_vector_type(8)));
typedef float  f32x4  __attribute__((ext_vector_type(4)));

// ---------------- species bucketing ----------------

__global__ void k_count(const int* __restrict__ sp, int n, int* __restrict__ counts) {
    __shared__ int h[NSPEC];
    if (threadIdx.x < NSPEC) h[threadIdx.x] = 0;
    __syncthreads();
    for (int i = blockIdx.x * blockDim.x + threadIdx.x; i < n; i += gridDim.x * blockDim.x)
        atomicAdd(&h[sp[i]], 1);
    __syncthreads();
    if (threadIdx.x < NSPEC) atomicAdd(&counts[threadIdx.x], h[threadIdx.x]);
}

__global__ void k_scatter(const int* __restrict__ sp, int n,
                          const int* __restrict__ counts, int* __restrict__ cursors,
                          int* __restrict__ order) {
    __shared__ int lh[NSPEC];
    __shared__ int basep[NSPEC];
    if (threadIdx.x < NSPEC) lh[threadIdx.x] = 0;
    __syncthreads();
    int i = blockIdx.x * blockDim.x + threadIdx.x;
    int s = (i < n) ? sp[i] : -1;
    int local = 0;
    if (s >= 0) local = atomicAdd(&lh[s], 1);
    __syncthreads();
    if (threadIdx.x < NSPEC) {
        int q = threadIdx.x;
        int off = 0;
        for (int u = 0; u < q; ++u) off += counts[u];
        basep[q] = off + atomicAdd(&cursors[q], lh[q]);
    }
    __syncthreads();
    if (s >= 0) order[basep[s] + local] = i;
}

// ---------------- build per-species Gram matrix, sigma-permuted fragment-major ----------------
// G[s][c][k] = sum_m w[s][m]*sup[s][m][c]*sup[s][m][k]  (fp32 accum -> bf16)
// t = ((s*8+ct)*4+kk)*64+lane holds G[s][sigma(ct,lane&15)][kk*32+(lane>>4)*8+u], u=0..7
// sigma(ct,i) = (ct>>1)*32 + (i>>2)*8 + (ct&1)*4 + (i&3): MFMA D-layout lands z[c] on
// the lane that already holds x[c] -> pairing needs no cross-lane moves.

__global__ void k_buildG(const float* __restrict__ sup, const float* __restrict__ w,
                         __bf16* __restrict__ gfrag) {
    const int t = blockIdx.x * blockDim.x + threadIdx.x;   // 8192 total
    if (t >= NSPEC * 8 * 4 * 64) return;
    const int lane = t & 63;
    const int kk   = (t >> 6) & 3;
    const int ct   = (t >> 8) & 7;
    const int s    = t >> 11;
    const int i    = lane & 15;
    const int c    = (ct >> 1) * 32 + (i >> 2) * 8 + (ct & 1) * 4 + (i & 3);
    const int k0   = kk * 32 + (lane >> 4) * 8;
    const float* S = sup + (size_t)s * NSUP * KF;
    const float* W = w + s * NSUP;
    float a0 = 0.f, a1 = 0.f, a2 = 0.f, a3 = 0.f, a4 = 0.f, a5 = 0.f, a6 = 0.f, a7 = 0.f;
    for (int m = 0; m < NSUP; ++m) {
        const float wc = W[m] * S[m * KF + c];
        const float4 ka = *(const float4*)(S + m * KF + k0);
        const float4 kb = *(const float4*)(S + m * KF + k0 + 4);
        a0 += wc * ka.x; a1 += wc * ka.y; a2 += wc * ka.z; a3 += wc * ka.w;
        a4 += wc * kb.x; a5 += wc * kb.y; a6 += wc * kb.z; a7 += wc * kb.w;
    }
    bf16x8 o;
    o[0] = (__bf16)a0; o[1] = (__bf16)a1; o[2] = (__bf16)a2; o[3] = (__bf16)a3;
    o[4] = (__bf16)a4; o[5] = (__bf16)a5; o[6] = (__bf16)a6; o[7] = (__bf16)a7;
    *(bf16x8*)(gfrag + (size_t)t * 8) = o;
}

// ---------------- helpers ----------------

__device__ __forceinline__ bf16x8 pack8(float4 a, float4 b) {
    bf16x8 o;
    o[0] = (__bf16)a.x; o[1] = (__bf16)a.y; o[2] = (__bf16)a.z; o[3] = (__bf16)a.w;
    o[4] = (__bf16)b.x; o[5] = (__bf16)b.y; o[6] = (__bf16)b.z; o[7] = (__bf16)b.w;
    return o;
}

__device__ __forceinline__ float sq4(float4 a) {
    return a.x * a.x + a.y * a.y + a.z * a.z + a.w * a.w;
}

// One ct-step (single species, single atom-set): 4 G-fragment LDS reads,
// 4 chained MFMA, pair acc[j] with own-lane x from fragment XF ((CT&1)*4 .. +3).
#define GSTEP(CT, XF)                                                           \
    {                                                                           \
        const __bf16* gq = gp + (CT) * 2048;                                    \
        f32x4 acc = (f32x4){0.f, 0.f, 0.f, 0.f};                                \
        acc = __builtin_amdgcn_mfma_f32_16x16x32_bf16(                          \
            *(const bf16x8*)(gq), xf0, acc, 0, 0, 0);                           \
        acc = __builtin_amdgcn_mfma_f32_16x16x32_bf16(                          \
            *(const bf16x8*)(gq + 512), xf1, acc, 0, 0, 0);                     \
        acc = __builtin_amdgcn_mfma_f32_16x16x32_bf16(                          \
            *(const bf16x8*)(gq + 1024), xf2, acc, 0, 0, 0);                    \
        acc = __builtin_amdgcn_mfma_f32_16x16x32_bf16(                          \
            *(const bf16x8*)(gq + 1536), xf3, acc, 0, 0, 0);                    \
        es += acc[0] * (float)XF[((CT) & 1) * 4 + 0]                            \
            + acc[1] * (float)XF[((CT) & 1) * 4 + 1]                            \
            + acc[2] * (float)XF[((CT) & 1) * 4 + 2]                            \
            + acc[3] * (float)XF[((CT) & 1) * 4 + 3];                           \
    }

// ---------------- main kernel: species-pure + 32 KB LDS G + in-flight prefetch ----------------
// Block's species = blockIdx & 3. Atoms from the species bucket (order[]).
// r11's pipeline: rows of tile t+gs issued BEFORE tile t's compute; idx 2-ahead.

__global__ __launch_bounds__(BLOCK, 1) void k_main(
    const float* __restrict__ ps,
    const __bf16* __restrict__ gfrag,
    const int* __restrict__ counts,
    const int* __restrict__ order,
    const int* __restrict__ sids,
    float* __restrict__ out,
    int n)
{
    __shared__ __align__(16) __bf16 Glds[128 * 128];   // 32 KB (one species)

    const int spec = blockIdx.x & 3;
    {
        const int4* src = (const int4*)(gfrag + (size_t)spec * 16384);
        for (int f = threadIdx.x; f < 2048; f += BLOCK)
            ((int4*)Glds)[f] = src[f];
    }
    __syncthreads();

    int off = 0;
    if (spec > 0) off += counts[0];
    if (spec > 1) off += counts[1];
    if (spec > 2) off += counts[2];
    const int cnt = counts[spec];

    const int lane = threadIdx.x & 63;
    const int r = lane & 15, g = lane >> 4;
    const int wsp = (blockIdx.x >> 2) * (BLOCK / 64) + (threadIdx.x >> 6);
    const int gs  = (GRID / 4) * (BLOCK / 64);
    const int ntiles = (cnt + 15) / 16;
    if (wsp >= ntiles) return;

    const float4 z4 = make_float4(0.f, 0.f, 0.f, 0.f);

    // ---- prologue: tile wsp's rows + sid; idx for wsp+gs ----
    bool v;
    int sid;
    float4 pf0, pf1, pf2, pf3, pf4, pf5, pf6, pf7;
    {
        int l0 = wsp * 16 + r;
        v = l0 < cnt;
        int ra = v ? order[off + l0] : 0;
        sid = v ? sids[ra] : 0;
        const float* p = ps + (size_t)ra * KF + g * 8;
        pf0 = v ? *(const float4*)(p +   0) : z4;
        pf1 = v ? *(const float4*)(p +   4) : z4;
        pf2 = v ? *(const float4*)(p +  32) : z4;
        pf3 = v ? *(const float4*)(p +  36) : z4;
        pf4 = v ? *(const float4*)(p +  64) : z4;
        pf5 = v ? *(const float4*)(p +  68) : z4;
        pf6 = v ? *(const float4*)(p +  96) : z4;
        pf7 = v ? *(const float4*)(p + 100) : z4;
    }
    bool nv = false;
    int nra = 0;
    {
        int tn = wsp + gs;
        if (tn < ntiles) {
            int l = tn * 16 + r;
            if (l < cnt) { nra = order[off + l]; nv = true; }
        }
    }

    for (int t = wsp; t < ntiles; t += gs) {
        // ---- consume current rows: norm (fp32) + bf16 fragments ----
        float nn = sq4(pf0) + sq4(pf1) + sq4(pf2) + sq4(pf3)
                 + sq4(pf4) + sq4(pf5) + sq4(pf6) + sq4(pf7);
        nn += __shfl_xor(nn, 16);
        nn += __shfl_xor(nn, 32);
        const bf16x8 xf0 = pack8(pf0, pf1);
        const bf16x8 xf1 = pack8(pf2, pf3);
        const bf16x8 xf2 = pack8(pf4, pf5);
        const bf16x8 xf3 = pack8(pf6, pf7);
        const bool  curV   = v;
        const int   curSid = sid;

        // ---- issue next tile's rows + sid (in flight under compute) ----
        const int tn = t + gs;
        if (tn < ntiles) {
            v = nv;
            int ra = nv ? nra : 0;
            sid = v ? sids[ra] : 0;
            const float* p2 = ps + (size_t)ra * KF + g * 8;
            pf0 = v ? *(const float4*)(p2 +   0) : z4;
            pf1 = v ? *(const float4*)(p2 +   4) : z4;
            pf2 = v ? *(const float4*)(p2 +  32) : z4;
            pf3 = v ? *(const float4*)(p2 +  36) : z4;
            pf4 = v ? *(const float4*)(p2 +  64) : z4;
            pf5 = v ? *(const float4*)(p2 +  68) : z4;
            pf6 = v ? *(const float4*)(p2 +  96) : z4;
            pf7 = v ? *(const float4*)(p2 + 100) : z4;
        }
        // ---- issue idx for t+2gs ----
        nv = false;
        {
            int t2 = t + 2 * gs;
            if (t2 < ntiles) {
                int l = t2 * 16 + r;
                if (l < cnt) { nra = order[off + l]; nv = true; }
            }
        }

        // ---- compute: 8 ct-steps, single species ----
        const __bf16* gp = Glds + lane * 8;
        float es = 0.f;
        GSTEP(0, xf0)
        GSTEP(1, xf0)
        __builtin_amdgcn_sched_barrier(0);
        GSTEP(2, xf1)
        GSTEP(3, xf1)
        __builtin_amdgcn_sched_barrier(0);
        GSTEP(4, xf2)
        GSTEP(5, xf2)
        __builtin_amdgcn_sched_barrier(0);
        GSTEP(6, xf3)
        GSTEP(7, xf3)

        float u = (curV && nn > 0.f) ? es / nn : 0.f;   // g-slice partial, atom r

        // ---- emit ----
        const int s0 = __shfl(curSid, 0);
        const bool uni = __all(curSid == s0);
        if (uni) {
            float tot = u;
            tot += __shfl_xor(tot, 1);  tot += __shfl_xor(tot, 2);
            tot += __shfl_xor(tot, 4);  tot += __shfl_xor(tot, 8);
            tot += __shfl_xor(tot, 16); tot += __shfl_xor(tot, 32);
            if (lane == 0 && tot != 0.f) atomicAdd(&out[s0], tot);
        } else {
            u += __shfl_xor(u, 16);
            u += __shfl_xor(u, 32);
            if (g == 0 && curV) atomicAdd(&out[curSid], u);
        }
    }
}

// ---------------- slow-but-correct fallback (ws too small) ----------------

__global__ void k_fallback(const float* __restrict__ ps, const float* __restrict__ support,
                           const float* __restrict__ weights, const int* __restrict__ species,
                           const int* __restrict__ struct_ids, float* __restrict__ out, int n)
{
    int gw = (blockIdx.x * blockDim.x + threadIdx.x) >> 6;
    int lane = threadIdx.x & 63;
    int nw = (gridDim.x * blockDim.x) >> 6;
    for (int atom = gw; atom < n; atom += nw) {
        const float* row = ps + (size_t)atom * KF;
        float x0 = row[lane], x1 = row[lane + 64];
        float nsum = x0 * x0 + x1 * x1;
        for (int o = 32; o; o >>= 1) nsum += __shfl_xor(nsum, o);
        float iv2 = 1.0f / nsum;
        int s = species[atom];
        const float* sup = support + (size_t)s * NSUP * KF;
        const float* w = weights + (size_t)s * NSUP;
        float e = 0.f;
        for (int mm = 0; mm < 4; ++mm) {
            int m = lane + mm * 64;
            const float* srow = sup + (size_t)m * KF;
            float d = 0.f;
            for (int k = 0; k < KF; ++k) d += row[k] * srow[k];
            e += d * d * w[m];
        }
        for (int o = 32; o; o >>= 1) e += __shfl_xor(e, o);
        if (lane == 0) atomicAdd(&out[struct_ids[atom]], e * iv2);
    }
}

// ---------------- launch ----------------

extern "C" void kernel_launch(void* const* d_in, const int* in_sizes, int n_in,
                              void* d_out, int out_size, void* d_ws, size_t ws_size,
                              hipStream_t stream)
{
    const float* ps       = (const float*)d_in[0];
    const float* support  = (const float*)d_in[1];
    const float* weights  = (const float*)d_in[2];
    const int*   species  = (const int*)d_in[3];
    const int*   sids     = (const int*)d_in[4];
    float* out = (float*)d_out;
    const int n = in_sizes[0] / KF;

    hipMemsetAsync(d_out, 0, (size_t)out_size * sizeof(float), stream);

    const size_t gbytes = (size_t)NSPEC * 8 * 4 * 64 * 8 * sizeof(__bf16);   // 128 KB
    size_t order_end = 64 + (size_t)n * sizeof(int);
    size_t gfrag_off = (order_end + 15) & ~(size_t)15;
    const size_t need = gfrag_off + gbytes;
    if (ws_size < need) {
        k_fallback<<<2048, 256, 0, stream>>>(ps, support, weights, species, sids, out, n);
        return;
    }

    int* ws      = (int*)d_ws;
    int* counts  = ws;        // [0..3]
    int* cursors = ws + 8;    // [8..11]
    int* order   = ws + 16;
    __bf16* gfrag = (__bf16*)((char*)d_ws + gfrag_off);

    hipMemsetAsync(ws, 0, 64, stream);
    k_count<<<512, 256, 0, stream>>>(species, n, counts);
    k_scatter<<<(n + 255) / 256, 256, 0, stream>>>(species, n, counts, cursors, order);
    k_buildG<<<(NSPEC * 8 * 4 * 64 + 255) / 256, 256, 0, stream>>>(support, weights, gfrag);

    k_main<<<GRID, BLOCK, 0, stream>>>(ps, gfrag, counts, order, sids, out, n);
}